// Round 2
// baseline (18634.900 us; speedup 1.0000x reference)
//
#include <hip/hip_runtime.h>
#include <hip/hip_bf16.h>

// ---------- types ----------
typedef short    bf16x8 __attribute__((ext_vector_type(8)));   // 8 bf16 (4 VGPRs), MFMA A/B frag
typedef float    f32x4  __attribute__((ext_vector_type(4)));   // MFMA C/D frag
typedef unsigned short u16x8 __attribute__((ext_vector_type(8)));

#define B_  64
#define S_  128
#define T_  128
#define E_  1024
#define H_  1024
#define NBLK 256

__device__ __forceinline__ unsigned short f2bf(float f) {
    unsigned u = __float_as_uint(f);
    unsigned r = (u + 0x7FFFu + ((u >> 16) & 1u)) >> 16;   // RNE
    return (unsigned short)r;
}
__device__ __forceinline__ float bf2f(unsigned short u) {
    return __uint_as_float((unsigned)u << 16);
}
__device__ __forceinline__ float my_tanh(float x) {
    float e = __expf(2.0f * x);
    return 1.0f - 2.0f / (e + 1.0f);
}
__device__ __forceinline__ float my_sig(float x) {
    return 1.0f / (1.0f + __expf(-x));
}

// ---------- device-scope grid barrier (counter + generation) ----------
__device__ __forceinline__ void gbar(int* cnt, int* gen) {
    __syncthreads();
    if (threadIdx.x == 0) {
        __threadfence();   // release all prior writes device-wide
        int g = __hip_atomic_load(gen, __ATOMIC_RELAXED, __HIP_MEMORY_SCOPE_AGENT);
        int prev = __hip_atomic_fetch_add(cnt, 1, __ATOMIC_ACQ_REL, __HIP_MEMORY_SCOPE_AGENT);
        if (prev == NBLK - 1) {
            __hip_atomic_store(cnt, 0, __ATOMIC_RELAXED, __HIP_MEMORY_SCOPE_AGENT);
            __hip_atomic_store(gen, g + 1, __ATOMIC_RELEASE, __HIP_MEMORY_SCOPE_AGENT);
        } else {
            while (__hip_atomic_load(gen, __ATOMIC_ACQUIRE, __HIP_MEMORY_SCOPE_AGENT) == g) {
                __builtin_amdgcn_s_sleep(1);
            }
        }
    }
    __syncthreads();
}

// ---------- f32 -> bf16 conversion ----------
__global__ void k_cvt(const float* __restrict__ s, unsigned short* __restrict__ d, long n) {
    long i = ((long)blockIdx.x * blockDim.x + threadIdx.x) * 4;
    if (i >= n) return;
    float4 f = *(const float4*)(s + i);
    ushort4 o;
    o.x = f2bf(f.x); o.y = f2bf(f.y); o.z = f2bf(f.z); o.w = f2bf(f.w);
    *(ushort4*)(d + i) = o;
}

// trg_embed (B,T,1024) -> preC[(b*T+t)*4096 + 0..1023]
__global__ void k_cvt_te(const float* __restrict__ s, unsigned short* __restrict__ d, long n) {
    long i = ((long)blockIdx.x * blockDim.x + threadIdx.x) * 4;
    if (i >= n) return;
    float4 f = *(const float4*)(s + i);
    long row = i >> 10, col = i & 1023;
    ushort4 o;
    o.x = f2bf(f.x); o.y = f2bf(f.y); o.z = f2bf(f.z); o.w = f2bf(f.w);
    *(ushort4*)(d + row * 4096 + col) = o;
}

// ---------- generic MFMA GEMM: C[M,N] = A[M,K] @ W[N,K]^T ----------
template<int OUTBF>
__global__ __launch_bounds__(256) void k_gemm(const unsigned short* __restrict__ A, long lda,
                                              const unsigned short* __restrict__ W, long ldw,
                                              void* __restrict__ Cv, long ldc, int K) {
    const int lane = threadIdx.x & 63;
    const int wv   = threadIdx.x >> 6;
    const int r    = lane & 15, g = lane >> 4;
    const long m0  = (long)blockIdx.y * 64 + wv * 16;
    const long n0  = (long)blockIdx.x * 64;
    const unsigned short* a  = A + (m0 + r) * lda + g * 8;
    const unsigned short* w0 = W + (n0 + r) * ldw + g * 8;
    f32x4 acc[4] = {};
    for (int k = 0; k < K; k += 32) {
        bf16x8 av = *(const bf16x8*)(a + k);
#pragma unroll
        for (int j = 0; j < 4; ++j) {
            bf16x8 bv = *(const bf16x8*)(w0 + (long)j * 16 * ldw + k);
            acc[j] = __builtin_amdgcn_mfma_f32_16x16x32_bf16(av, bv, acc[j], 0, 0, 0);
        }
    }
#pragma unroll
    for (int j = 0; j < 4; ++j) {
        long row = m0 + g * 4;
        long col = n0 + j * 16 + r;
#pragma unroll
        for (int rr = 0; rr < 4; ++rr) {
            float v = acc[j][rr];
            if (OUTBF) ((unsigned short*)Cv)[(row + rr) * ldc + col] = f2bf(v);
            else       ((float*)Cv)[(row + rr) * ldc + col] = v;
        }
    }
}

// ---------- h0 activation ----------
__global__ void k_h0act(const float* __restrict__ hp, const float* __restrict__ bb,
                        float* __restrict__ h, unsigned short* __restrict__ hbf) {
    int i = blockIdx.x * 256 + threadIdx.x;   // 65536
    float v = my_tanh(hp[i] + bb[i & 1023]);
    h[i] = v; hbf[i] = f2bf(v);
}

// ---------- persistent step-loop kernel: all 128 steps, 4 phases/step ----------
__global__ __launch_bounds__(256, 2) void k_steps(
        const unsigned short* __restrict__ pk, const unsigned short* __restrict__ eh,
        const unsigned short* __restrict__ whp, const unsigned short* __restrict__ wih,
        const float* __restrict__ We, const float* __restrict__ gix,
        const float* __restrict__ bih, const float* __restrict__ bhh,
        float* __restrict__ h, unsigned short* __restrict__ hbf,
        float* __restrict__ hp, float* __restrict__ sc,
        unsigned short* __restrict__ preC,
        float* __restrict__ o_states, float* __restrict__ o_hf,
        int* cnt, int* gen) {
    __shared__ float smem[3 * 16 * 17];          // P2b: alpha[128]+red[4]; P3: gate staging
    const int g    = blockIdx.x;
    const int tid  = threadIdx.x;
    const int wv   = tid >> 6, lane = tid & 63;
    const int r    = lane & 15, gg = lane >> 4;

#pragma unroll 1
    for (int t = 0; t < T_; ++t) {
        // ---- P1: hp[64,4096] = hbf[64,1024] @ whp[4096,1024]^T ; block g -> 16 cols ----
        {
            const int n0 = g * 16;
            const unsigned short* a  = hbf + (long)(wv * 16 + r) * 1024 + gg * 8;
            const unsigned short* bw = whp + (long)(n0 + r) * 1024 + gg * 8;
            f32x4 acc = {};
#pragma unroll 4
            for (int k = 0; k < 1024; k += 32) {
                bf16x8 av = *(const bf16x8*)(a + k);
                bf16x8 bv = *(const bf16x8*)(bw + k);
                acc = __builtin_amdgcn_mfma_f32_16x16x32_bf16(av, bv, acc, 0, 0, 0);
            }
            const int row = wv * 16 + gg * 4;
#pragma unroll
            for (int rr = 0; rr < 4; ++rr)
                hp[(long)(row + rr) * 4096 + n0 + r] = acc[rr];
        }
        gbar(cnt, gen);

        // ---- P2a: energy scores; block g -> batch g>>2, 32 scores ----
        {
            const int b = g >> 2, s0 = (g & 3) * 32;
            const float* qp = hp + (long)b * 4096;
            float q[16], w[16];
#pragma unroll
            for (int i = 0; i < 16; ++i) { q[i] = qp[lane * 16 + i]; w[i] = We[lane * 16 + i]; }
#pragma unroll 1
            for (int ss = 0; ss < 8; ++ss) {
                int s = s0 + wv * 8 + ss;
                const unsigned short* row = pk + ((long)b * S_ + s) * 1024 + lane * 16;
                u16x8 v0 = *(const u16x8*)(row);
                u16x8 v1 = *(const u16x8*)(row + 8);
                float acc = 0.f;
#pragma unroll
                for (int i = 0; i < 8; ++i) acc += my_tanh(q[i] + bf2f(v0[i])) * w[i];
#pragma unroll
                for (int i = 0; i < 8; ++i) acc += my_tanh(q[8 + i] + bf2f(v1[i])) * w[8 + i];
#pragma unroll
                for (int off = 32; off; off >>= 1) acc += __shfl_xor(acc, off);
                if (lane == 0) sc[b * S_ + s] = acc;
            }
        }
        gbar(cnt, gen);

        // ---- P2b: softmax (redundant per block) + context slice of 512 cols ----
        {
            const int b = g >> 2, c0 = (g & 3) * 512;
            float* al  = smem;
            float* red = smem + 128;
            float e = 0.f;
            if (tid < 128) {
                float m = sc[b * S_ + tid];
#pragma unroll
                for (int off = 32; off; off >>= 1) m = fmaxf(m, __shfl_xor(m, off));
                if ((tid & 63) == 0) red[tid >> 6] = m;
            }
            __syncthreads();
            if (tid < 128) {
                float M = fmaxf(red[0], red[1]);
                e = __expf(sc[b * S_ + tid] - M);
                float s = e;
#pragma unroll
                for (int off = 32; off; off >>= 1) s += __shfl_xor(s, off);
                if ((tid & 63) == 0) red[2 + (tid >> 6)] = s;
            }
            __syncthreads();
            if (tid < 128) al[tid] = e / (red[2] + red[3]);
            __syncthreads();
            const int col = c0 + tid * 2;
            const unsigned short* ehp = eh + (long)b * S_ * 2048 + col;
            float a0 = 0.f, a1 = 0.f;
#pragma unroll 4
            for (int s = 0; s < S_; ++s) {
                float alv = al[s];
                ushort2 v = *(const ushort2*)(ehp + (long)s * 2048);
                a0 += alv * bf2f(v.x); a1 += alv * bf2f(v.y);
            }
            ushort2 o; o.x = f2bf(a0); o.y = f2bf(a1);
            *(ushort2*)(preC + ((long)b * T_ + t) * 4096 + 2048 + col) = o;
        }
        gbar(cnt, gen);

        // ---- P3: gi_ctx MFMA (wave=chunk) + GRU gates; block g -> j-tile g>>2, batches (g&3)*16 ----
        {
            const int jt = g >> 2, mb = g & 3;
            const int j0 = jt * 16, b0 = mb * 16;
            if (wv < 3) {
                const unsigned short* a  = preC + ((long)(b0 + r) * T_ + t) * 4096 + 2048 + gg * 8;
                const unsigned short* bw = wih + (long)(wv * 1024 + j0 + r) * 3072 + 1024 + gg * 8;
                f32x4 acc = {};
#pragma unroll 4
                for (int k = 0; k < 2048; k += 32) {
                    bf16x8 av = *(const bf16x8*)(a + k);
                    bf16x8 bv = *(const bf16x8*)(bw + k);
                    acc = __builtin_amdgcn_mfma_f32_16x16x32_bf16(av, bv, acc, 0, 0, 0);
                }
#pragma unroll
                for (int rr = 0; rr < 4; ++rr)
                    smem[(wv * 16 + gg * 4 + rr) * 17 + r] = acc[rr];
            }
            __syncthreads();
            const int lr = tid >> 4, lc = tid & 15;
            const int b = b0 + lr, j = j0 + lc;
            const long bt = (long)b * T_ + t;
            float g0 = smem[(0 * 16 + lr) * 17 + lc];
            float g1 = smem[(1 * 16 + lr) * 17 + lc];
            float g2 = smem[(2 * 16 + lr) * 17 + lc];
            float grv = gix[bt * 3072 + j]        + g0 + bih[j]        + hp[(long)b * 4096 + 1024 + j] + bhh[j];
            float gzv = gix[bt * 3072 + 1024 + j] + g1 + bih[1024 + j] + hp[(long)b * 4096 + 2048 + j] + bhh[1024 + j];
            float gni = gix[bt * 3072 + 2048 + j] + g2 + bih[2048 + j];
            float ghn = hp[(long)b * 4096 + 3072 + j] + bhh[2048 + j];
            float rg = my_sig(grv);
            float zg = my_sig(gzv);
            float nv = my_tanh(gni + rg * ghn);
            float ho = h[(long)b * 1024 + j];
            float hn = (1.f - zg) * nv + zg * ho;
            h[(long)b * 1024 + j] = hn;
            unsigned short hb = f2bf(hn);
            hbf[(long)b * 1024 + j] = hb;
            preC[bt * 4096 + 1024 + j] = hb;
            o_states[bt * 1024 + j] = hn;
            if (t == T_ - 1) o_hf[(long)b * 1024 + j] = hn;
        }
        gbar(cnt, gen);
    }
}

// ---------- host ----------
extern "C" void kernel_launch(void* const* d_in, const int* in_sizes, int n_in,
                              void* d_out, int out_size, void* d_ws, size_t ws_size,
                              hipStream_t stream) {
    const float* te  = (const float*)d_in[0];
    const float* eh  = (const float*)d_in[1];
    const float* ef  = (const float*)d_in[2];
    const float* Wb  = (const float*)d_in[5];
    const float* bb  = (const float*)d_in[6];
    const float* Wk  = (const float*)d_in[7];
    const float* Wq  = (const float*)d_in[8];
    const float* We  = (const float*)d_in[9];
    const float* Wih = (const float*)d_in[10];
    const float* Whh = (const float*)d_in[11];
    const float* bih = (const float*)d_in[12];
    const float* bhh = (const float*)d_in[13];
    const float* Wpre= (const float*)d_in[14];

    char* ws = (char*)d_ws;
    if (ws_size < 272236544UL) return;   // loud failure (output stays poisoned)
    float*          h     = (float*)(ws + 0);                  // 64*1024*4
    float*          hp    = (float*)(ws + 262144);             // 64*4096*4
    unsigned short* hbf   = (unsigned short*)(ws + 1310720);   // 64*1024*2
    unsigned short* efb   = (unsigned short*)(ws + 1441792);   // 64*2048*2 (init only)
    float*          sc    = (float*)(ws + 1441792);            // aliases efb: 64*128*4 (scores)
    int*            syncb = (int*)(ws + 1441792 + 65536);      // cnt @+0, gen @+128B (inside efb region)
    unsigned short* ehb   = (unsigned short*)(ws + 1703936);   // B*S*2048*2
    unsigned short* pkb   = (unsigned short*)(ws + 35258368);  // B*S*1024*2
    unsigned short* preC  = (unsigned short*)(ws + 52035584);  // B*T*4096*2
    float*          gix   = (float*)(ws + 119144448);          // B*T*3072*4
    unsigned short* wbb   = (unsigned short*)(ws + 219807744); // 1024*2048*2
    unsigned short* wkb   = (unsigned short*)(ws + 224002048); // 1024*2048*2
    unsigned short* whpb  = (unsigned short*)(ws + 228196352); // 4096*1024*2
    unsigned short* wihb  = (unsigned short*)(ws + 236584960); // 3072*3072*2
    unsigned short* wpreb = (unsigned short*)(ws + 255459328); // 2048*4096*2

    float* o_states = (float*)d_out;                 // (B,T,H)
    float* o_hf     = o_states + (long)B_ * T_ * H_; // (1,B,H)
    float* o_pre    = o_hf + (long)B_ * H_;          // (B,T,2H)

    auto cvt = [&](const float* s, unsigned short* d, long n) {
        k_cvt<<<dim3((unsigned)((n / 4 + 255) / 256)), 256, 0, stream>>>(s, d, n);
    };
    cvt(eh,  ehb,  (long)B_ * S_ * 2048);
    cvt(ef,  efb,  (long)B_ * 2048);
    cvt(Wb,  wbb,  1024L * 2048);
    cvt(Wk,  wkb,  1024L * 2048);
    cvt(Wq,  whpb, 1024L * 1024);
    cvt(Whh, whpb + 1024L * 1024, 3072L * 1024);
    cvt(Wih, wihb, 3072L * 3072);
    cvt(Wpre,wpreb,2048L * 4096);
    k_cvt_te<<<8192, 256, 0, stream>>>(te, preC, (long)B_ * T_ * 1024);

    // h0 = tanh(encoder_final @ W_bridge^T + b_bridge)  (consumes efb)
    k_gemm<0><<<dim3(16, 1), 256, 0, stream>>>(efb, 2048, wbb, 2048, hp, 1024, 2048);
    k_h0act<<<256, 256, 0, stream>>>(hp, bb, h, hbf);
    // efb no longer needed -> reset barrier vars (stream-ordered, deterministic per call)
    hipMemsetAsync(syncb, 0, 256, stream);
    // proj_key = encoder_hidden @ W_key^T  (bf16 out)
    k_gemm<1><<<dim3(16, 128), 256, 0, stream>>>(ehb, 2048, wkb, 2048, pkb, 1024, 2048);
    // gi_x = trg_embed @ W_ih[:, :E]^T  (f32 out)
    k_gemm<0><<<dim3(48, 128), 256, 0, stream>>>(preC, 4096, wihb, 3072, gix, 3072, 1024);

    // persistent step loop (all 128 steps, grid barrier between phases)
    k_steps<<<NBLK, 256, 0, stream>>>(pkb, ehb, whpb, wihb, We, gix, bih, bhh,
                                      h, hbf, hp, sc, preC, o_states, o_hf,
                                      syncb, syncb + 32);

    // pre_output = [x_t, h_t, ctx_t] @ W_pre^T
    k_gemm<0><<<dim3(32, 128), 256, 0, stream>>>(preC, 4096, wpreb, 4096, o_pre, 2048, 4096);
}